// Round 4
// baseline (4947.456 us; speedup 1.0000x reference)
//
#include <hip/hip_runtime.h>

#define NPTS 2048
#define NB   16

// eps = 0.01, log-domain Sinkhorn in base-2.
constexpr float K_R          = 144.26950408889634f;    // log2(e)/eps
constexpr float K_TWO_R      = 288.53900817779268f;    // 2*K_R
constexpr float K_EPS_LN2    = 0.0069314718055994531f; // eps*ln2
constexpr float K_EPS_LOGMRG = -0.076246189861593985f; // eps*ln(1/2048)

__device__ __forceinline__ float fexp2(float x) { return __builtin_amdgcn_exp2f(x); }
__device__ __forceinline__ float flog2(float x) { return __builtin_amdgcn_logf(x); }

// device-coherent dual access (bypasses non-coherent per-XCD L2)
__device__ __forceinline__ float aload(const float* p) {
    return __hip_atomic_load(p, __ATOMIC_RELAXED, __HIP_MEMORY_SCOPE_AGENT);
}
__device__ __forceinline__ void astore(float* p, float v) {
    __hip_atomic_store(p, v, __ATOMIC_RELAXED, __HIP_MEMORY_SCOPE_AGENT);
}

// ---------------------------------------------------------------- prep ------
__global__ __launch_bounds__(256) void prep_kernel(
    const float* __restrict__ x, const float* __restrict__ y,
    float4* __restrict__ px, float4* __restrict__ py, float* __restrict__ g)
{
    int idx = blockIdx.x * 256 + threadIdx.x;
    if (idx >= NB * NPTS) return;
    float x0 = x[idx*3+0], x1 = x[idx*3+1], x2 = x[idx*3+2];
    px[idx] = make_float4(x0, x1, x2, fmaf(x0,x0, fmaf(x1,x1, x2*x2)));
    float y0 = y[idx*3+0], y1 = y[idx*3+1], y2 = y[idx*3+2];
    py[idx] = make_float4(y0, y1, y2, fmaf(y0,y0, fmaf(y1,y1, y2*y2)));
    g[idx] = 0.0f;
}

// --------------------------------------------------------- batch barrier ----
// Monotonic 64-arrival barrier per batch; counter padded to its own line.
__device__ __forceinline__ void batch_barrier(unsigned* bar2, unsigned target) {
    __syncthreads();
    if (threadIdx.x == 0) {
        __hip_atomic_fetch_add(bar2, 1u, __ATOMIC_ACQ_REL, __HIP_MEMORY_SCOPE_AGENT);
        while (__hip_atomic_load(bar2, __ATOMIC_ACQUIRE, __HIP_MEMORY_SCOPE_AGENT)
               < target)
            __builtin_amdgcn_s_sleep(2);
    }
    __syncthreads();
}

// LDS panel stage: (p*2R, (dual - |p|^2)*R), XOR-swizzled by region
__device__ __forceinline__ void stage_from(const float4* pk, const float* duals,
                                           float4* ld, int tid) {
    #pragma unroll
    for (int i2 = 0; i2 < 8; ++i2) {
        int k = i2 * 256 + tid;
        float4 p = pk[i2];
        ld[i2*256 + (tid ^ i2)] =
            make_float4(p.x * K_TWO_R, p.y * K_TWO_R, p.z * K_TWO_R,
                        (aload(&duals[k]) - p.w) * K_R);
    }
}

// sum_j 2^{2R*(x.y) + (dual_j-|y_j|^2)R - |x|^2 R} over this thread's region
__device__ __forceinline__ float region_sum(const float4* ld, float4 xi, int q) {
    const float u0 = -xi.w * K_R;
    const float4* base = &ld[q * 256];
    const float4* p0 = base + (q ^ 0);
    const float4* p1 = base + (q ^ 1);
    const float4* p2 = base + (q ^ 2);
    const float4* p3 = base + (q ^ 3);
    const float4* p4 = base + (q ^ 4);
    const float4* p5 = base + (q ^ 5);
    const float4* p6 = base + (q ^ 6);
    const float4* p7 = base + (q ^ 7);

    float a0 = 0.f, a1 = 0.f, a2 = 0.f, a3 = 0.f;
    for (int c = 0; c < 256; c += 8) {
        float4 y0 = p0[c], y1 = p1[c], y2 = p2[c], y3 = p3[c];
        float4 y4 = p4[c], y5 = p5[c], y6 = p6[c], y7 = p7[c];
        float e0 = fexp2(fmaf(y0.x, xi.x, fmaf(y0.y, xi.y, fmaf(y0.z, xi.z, y0.w + u0))));
        float e1 = fexp2(fmaf(y1.x, xi.x, fmaf(y1.y, xi.y, fmaf(y1.z, xi.z, y1.w + u0))));
        float e2 = fexp2(fmaf(y2.x, xi.x, fmaf(y2.y, xi.y, fmaf(y2.z, xi.z, y2.w + u0))));
        float e3 = fexp2(fmaf(y3.x, xi.x, fmaf(y3.y, xi.y, fmaf(y3.z, xi.z, y3.w + u0))));
        float e4 = fexp2(fmaf(y4.x, xi.x, fmaf(y4.y, xi.y, fmaf(y4.z, xi.z, y4.w + u0))));
        float e5 = fexp2(fmaf(y5.x, xi.x, fmaf(y5.y, xi.y, fmaf(y5.z, xi.z, y5.w + u0))));
        float e6 = fexp2(fmaf(y6.x, xi.x, fmaf(y6.y, xi.y, fmaf(y6.z, xi.z, y6.w + u0))));
        float e7 = fexp2(fmaf(y7.x, xi.x, fmaf(y7.y, xi.y, fmaf(y7.z, xi.z, y7.w + u0))));
        a0 += e0; a1 += e1; a2 += e2; a3 += e3;
        a0 += e4; a1 += e5; a2 += e6; a3 += e7;
    }
    return (a0 + a1) + (a2 + a3);
}

// ------------------------------------------------------- persistent core ----
// Grid 1024 = 4 wgs/CU * 256 CU (co-resident; __launch_bounds__(256,4)).
// wg -> (batch b, chunk). 100 half-steps with per-batch barriers, then EMD.
__global__ __launch_bounds__(256, 4) void sinkhorn_fused(
    const float4* __restrict__ px, const float4* __restrict__ py,
    float* __restrict__ f, float* __restrict__ g,
    unsigned* __restrict__ bar, float* __restrict__ out)
{
    __shared__ float4 ld[NPTS];   // 32768 B

    const int b     = blockIdx.x >> 6;
    const int chunk = blockIdx.x & 63;
    const int tid   = threadIdx.x;
    const int q     = tid & 7;
    const int row   = chunk * 32 + (tid >> 3);

    const float4* pxb = px + b * NPTS;
    const float4* pyb = py + b * NPTS;
    float* fb = f + b * NPTS;
    float* gb = g + b * NPTS;
    unsigned* mybar = bar + b * 32;   // 128 B apart: no false sharing

    const float4 xf = pxb[row];   // x-row point (f-update & EMD)
    const float4 xg = pyb[row];   // y-row point (g-update)

    float4 pk[8];
    #pragma unroll
    for (int i2 = 0; i2 < 8; ++i2) pk[i2] = pyb[i2*256 + tid];

    unsigned target = 64;
    for (int it = 0; it < 50; ++it) {
        // ---- f-update: panel (py, g) ----
        stage_from(pk, gb, ld, tid);
        __syncthreads();
        #pragma unroll
        for (int i2 = 0; i2 < 8; ++i2) pk[i2] = pxb[i2*256 + tid];  // prefetch
        float s = region_sum(ld, xf, q);
        s += __shfl_xor(s, 1, 64);
        s += __shfl_xor(s, 2, 64);
        s += __shfl_xor(s, 4, 64);
        if (q == 0) astore(&fb[row], K_EPS_LOGMRG - K_EPS_LN2 * flog2(s));
        batch_barrier(mybar, target); target += 64;

        // ---- g-update: panel (px, f) ----
        stage_from(pk, fb, ld, tid);
        __syncthreads();
        #pragma unroll
        for (int i2 = 0; i2 < 8; ++i2) pk[i2] = pyb[i2*256 + tid];  // prefetch
        s = region_sum(ld, xg, q);
        s += __shfl_xor(s, 1, 64);
        s += __shfl_xor(s, 2, 64);
        s += __shfl_xor(s, 4, 64);
        if (q == 0) astore(&gb[row], K_EPS_LOGMRG - K_EPS_LN2 * flog2(s));
        batch_barrier(mybar, target); target += 64;
    }

    // ---- EMD: panel (y raw, (g-|y|^2)R); pk[] holds py points ----
    #pragma unroll
    for (int i2 = 0; i2 < 8; ++i2) {
        int k = i2 * 256 + tid;
        float4 p = pk[i2];
        ld[i2*256 + (tid ^ i2)] =
            make_float4(p.x, p.y, p.z, (aload(&gb[k]) - p.w) * K_R);
    }
    const float u2 = (aload(&fb[row]) - xf.w) * K_R;
    __syncthreads();

    {
        const float4* base = &ld[q * 256];
        const float4* p0 = base + (q ^ 0);
        const float4* p1 = base + (q ^ 1);
        const float4* p2 = base + (q ^ 2);
        const float4* p3 = base + (q ^ 3);
        const float4* p4 = base + (q ^ 4);
        const float4* p5 = base + (q ^ 5);
        const float4* p6 = base + (q ^ 6);
        const float4* p7 = base + (q ^ 7);

        float acc = 0.f;
        for (int c = 0; c < 256; c += 8) {
            float4 yv[8] = { p0[c], p1[c], p2[c], p3[c], p4[c], p5[c], p6[c], p7[c] };
            #pragma unroll
            for (int k = 0; k < 8; ++k) {
                float4 yj = yv[k];
                float d  = fmaf(yj.x, xf.x, fmaf(yj.y, xf.y, yj.z * xf.z));
                float y2 = fmaf(yj.x, yj.x, fmaf(yj.y, yj.y, yj.z * yj.z));
                float C  = fmaf(-2.0f, d, xf.w + y2);
                float t  = fmaf(K_TWO_R, d, u2 + yj.w);
                acc = fmaf(fexp2(t), C, acc);
            }
        }
        #pragma unroll
        for (int off = 1; off < 64; off <<= 1) acc += __shfl_xor(acc, off, 64);

        __syncthreads();                 // done reading panel; reuse as scratch
        float* wsum = (float*)ld;
        if ((tid & 63) == 0) wsum[tid >> 6] = acc;
        __syncthreads();
        if (tid == 0) atomicAdd(&out[b], wsum[0] + wsum[1] + wsum[2] + wsum[3]);
    }
}

// -------------------------------------------------------------- launch ------
extern "C" void kernel_launch(void* const* d_in, const int* in_sizes, int n_in,
                              void* d_out, int out_size, void* d_ws, size_t ws_size,
                              hipStream_t stream)
{
    const float* x = (const float*)d_in[0];
    const float* y = (const float*)d_in[1];
    float* out = (float*)d_out;

    char* ws = (char*)d_ws;
    float4*   px  = (float4*)(ws);
    float4*   py  = (float4*)(ws + (size_t)NB * NPTS * 16);
    float*    f   = (float*)  (ws + (size_t)NB * NPTS * 32);
    float*    g   = (float*)  (ws + (size_t)NB * NPTS * 32 + (size_t)NB * NPTS * 4);
    unsigned* bar = (unsigned*)(ws + (size_t)NB * NPTS * 32 + (size_t)NB * NPTS * 8);

    hipMemsetAsync(d_out, 0, (size_t)out_size * sizeof(float), stream);
    hipMemsetAsync(bar, 0, NB * 32 * sizeof(unsigned), stream);

    prep_kernel<<<(NB * NPTS + 255) / 256, 256, 0, stream>>>(x, y, px, py, g);
    sinkhorn_fused<<<NB * 64, 256, 0, stream>>>(px, py, f, g, bar, out);
}

// Round 5
// 2257.158 us; speedup vs baseline: 2.1919x; 2.1919x over previous
//
#include <hip/hip_runtime.h>

#define NPTS 2048
#define NB   16

// eps = 0.01, log-domain Sinkhorn in base-2.
constexpr float K_R          = 144.26950408889634f;    // log2(e)/eps
constexpr float K_TWO_R      = 288.53900817779268f;    // 2*K_R
constexpr float K_EPS_LN2    = 0.0069314718055994531f; // eps*ln2
constexpr float K_EPS_LOGMRG = -0.076246189861593985f; // eps*ln(1/2048)

__device__ __forceinline__ float fexp2(float x) { return __builtin_amdgcn_exp2f(x); }
__device__ __forceinline__ float flog2(float x) { return __builtin_amdgcn_logf(x); }

// device-coherent dual access (sc1: bypasses non-coherent per-XCD L2,
// served at the device coherence point). RELAXED: no cache invalidates.
__device__ __forceinline__ float aload(const float* p) {
    return __hip_atomic_load(p, __ATOMIC_RELAXED, __HIP_MEMORY_SCOPE_AGENT);
}
__device__ __forceinline__ void astore(float* p, float v) {
    __hip_atomic_store(p, v, __ATOMIC_RELAXED, __HIP_MEMORY_SCOPE_AGENT);
}

// ---------------------------------------------------------------- prep ------
__global__ __launch_bounds__(256) void prep_kernel(
    const float* __restrict__ x, const float* __restrict__ y,
    float4* __restrict__ px, float4* __restrict__ py, float* __restrict__ g)
{
    int idx = blockIdx.x * 256 + threadIdx.x;
    if (idx >= NB * NPTS) return;
    float x0 = x[idx*3+0], x1 = x[idx*3+1], x2 = x[idx*3+2];
    px[idx] = make_float4(x0, x1, x2, fmaf(x0,x0, fmaf(x1,x1, x2*x2)));
    float y0 = y[idx*3+0], y1 = y[idx*3+1], y2 = y[idx*3+2];
    py[idx] = make_float4(y0, y1, y2, fmaf(y0,y0, fmaf(y1,y1, y2*y2)));
    g[idx] = 0.0f;
}

// --------------------------------------------------------- batch barrier ----
// Monotonic 64-arrival per-batch barrier. NO acquire/release atomics:
// release ordering = s_waitcnt vmcnt(0) before a RELAXED fetch_add (dual
// stores are sc1 write-through; vmcnt(0) waits for their MALL acks, and the
// counter add reaches the same serialization point after them). Spin uses
// RELAXED loads -> no buffer_inv -> L2 keeps the px/py panels resident.
__device__ __forceinline__ void batch_barrier(unsigned* bar2, unsigned target) {
    __syncthreads();
    if (threadIdx.x == 0) {
        asm volatile("s_waitcnt vmcnt(0)" ::: "memory");
        __hip_atomic_fetch_add(bar2, 1u, __ATOMIC_RELAXED, __HIP_MEMORY_SCOPE_AGENT);
        while (__hip_atomic_load(bar2, __ATOMIC_RELAXED, __HIP_MEMORY_SCOPE_AGENT)
               < target)
            __builtin_amdgcn_s_sleep(2);
        asm volatile("" ::: "memory");
    }
    __syncthreads();
}

// LDS panel stage: (p*2R, (dual - |p|^2)*R), XOR-swizzled by region
__device__ __forceinline__ void stage_from(const float4* pk, const float* duals,
                                           float4* ld, int tid) {
    #pragma unroll
    for (int i2 = 0; i2 < 8; ++i2) {
        int k = i2 * 256 + tid;
        float4 p = pk[i2];
        ld[i2*256 + (tid ^ i2)] =
            make_float4(p.x * K_TWO_R, p.y * K_TWO_R, p.z * K_TWO_R,
                        (aload(&duals[k]) - p.w) * K_R);
    }
}

// sum_j 2^{2R*(x.y) + (dual_j-|y_j|^2)R - |x|^2 R} over this thread's region
__device__ __forceinline__ float region_sum(const float4* ld, float4 xi, int q) {
    const float u0 = -xi.w * K_R;
    const float4* base = &ld[q * 256];
    const float4* p0 = base + (q ^ 0);
    const float4* p1 = base + (q ^ 1);
    const float4* p2 = base + (q ^ 2);
    const float4* p3 = base + (q ^ 3);
    const float4* p4 = base + (q ^ 4);
    const float4* p5 = base + (q ^ 5);
    const float4* p6 = base + (q ^ 6);
    const float4* p7 = base + (q ^ 7);

    float a0 = 0.f, a1 = 0.f, a2 = 0.f, a3 = 0.f;
    for (int c = 0; c < 256; c += 8) {
        float4 y0 = p0[c], y1 = p1[c], y2 = p2[c], y3 = p3[c];
        float4 y4 = p4[c], y5 = p5[c], y6 = p6[c], y7 = p7[c];
        float e0 = fexp2(fmaf(y0.x, xi.x, fmaf(y0.y, xi.y, fmaf(y0.z, xi.z, y0.w + u0))));
        float e1 = fexp2(fmaf(y1.x, xi.x, fmaf(y1.y, xi.y, fmaf(y1.z, xi.z, y1.w + u0))));
        float e2 = fexp2(fmaf(y2.x, xi.x, fmaf(y2.y, xi.y, fmaf(y2.z, xi.z, y2.w + u0))));
        float e3 = fexp2(fmaf(y3.x, xi.x, fmaf(y3.y, xi.y, fmaf(y3.z, xi.z, y3.w + u0))));
        float e4 = fexp2(fmaf(y4.x, xi.x, fmaf(y4.y, xi.y, fmaf(y4.z, xi.z, y4.w + u0))));
        float e5 = fexp2(fmaf(y5.x, xi.x, fmaf(y5.y, xi.y, fmaf(y5.z, xi.z, y5.w + u0))));
        float e6 = fexp2(fmaf(y6.x, xi.x, fmaf(y6.y, xi.y, fmaf(y6.z, xi.z, y6.w + u0))));
        float e7 = fexp2(fmaf(y7.x, xi.x, fmaf(y7.y, xi.y, fmaf(y7.z, xi.z, y7.w + u0))));
        a0 += e0; a1 += e1; a2 += e2; a3 += e3;
        a0 += e4; a1 += e5; a2 += e6; a3 += e7;
    }
    return (a0 + a1) + (a2 + a3);
}

// ------------------------------------------------------- persistent core ----
// Grid 1024 = 4 wgs/CU * 256 CU (co-resident; __launch_bounds__(256,4)).
// wg -> (batch b, chunk). 100 half-steps with per-batch barriers, then EMD.
__global__ __launch_bounds__(256, 4) void sinkhorn_fused(
    const float4* __restrict__ px, const float4* __restrict__ py,
    float* __restrict__ f, float* __restrict__ g,
    unsigned* __restrict__ bar, float* __restrict__ out)
{
    __shared__ float4 ld[NPTS];   // 32768 B

    const int b     = blockIdx.x >> 6;
    const int chunk = blockIdx.x & 63;
    const int tid   = threadIdx.x;
    const int q     = tid & 7;
    const int row   = chunk * 32 + (tid >> 3);

    const float4* pxb = px + b * NPTS;
    const float4* pyb = py + b * NPTS;
    float* fb = f + b * NPTS;
    float* gb = g + b * NPTS;
    unsigned* mybar = bar + b * 32;   // 128 B apart: no false sharing

    const float4 xf = pxb[row];   // x-row point (f-update & EMD)
    const float4 xg = pyb[row];   // y-row point (g-update)

    float4 pk[8];
    #pragma unroll
    for (int i2 = 0; i2 < 8; ++i2) pk[i2] = pyb[i2*256 + tid];

    unsigned target = 64;
    for (int it = 0; it < 50; ++it) {
        // ---- f-update: panel (py, g) ----
        stage_from(pk, gb, ld, tid);
        __syncthreads();
        #pragma unroll
        for (int i2 = 0; i2 < 8; ++i2) pk[i2] = pxb[i2*256 + tid];  // prefetch
        float s = region_sum(ld, xf, q);
        s += __shfl_xor(s, 1, 64);
        s += __shfl_xor(s, 2, 64);
        s += __shfl_xor(s, 4, 64);
        if (q == 0) astore(&fb[row], K_EPS_LOGMRG - K_EPS_LN2 * flog2(s));
        batch_barrier(mybar, target); target += 64;

        // ---- g-update: panel (px, f) ----
        stage_from(pk, fb, ld, tid);
        __syncthreads();
        #pragma unroll
        for (int i2 = 0; i2 < 8; ++i2) pk[i2] = pyb[i2*256 + tid];  // prefetch
        s = region_sum(ld, xg, q);
        s += __shfl_xor(s, 1, 64);
        s += __shfl_xor(s, 2, 64);
        s += __shfl_xor(s, 4, 64);
        if (q == 0) astore(&gb[row], K_EPS_LOGMRG - K_EPS_LN2 * flog2(s));
        batch_barrier(mybar, target); target += 64;
    }

    // ---- EMD: panel (y raw, (g-|y|^2)R); pk[] holds py points ----
    #pragma unroll
    for (int i2 = 0; i2 < 8; ++i2) {
        int k = i2 * 256 + tid;
        float4 p = pk[i2];
        ld[i2*256 + (tid ^ i2)] =
            make_float4(p.x, p.y, p.z, (aload(&gb[k]) - p.w) * K_R);
    }
    const float u2 = (aload(&fb[row]) - xf.w) * K_R;
    __syncthreads();

    {
        const float4* base = &ld[q * 256];
        const float4* p0 = base + (q ^ 0);
        const float4* p1 = base + (q ^ 1);
        const float4* p2 = base + (q ^ 2);
        const float4* p3 = base + (q ^ 3);
        const float4* p4 = base + (q ^ 4);
        const float4* p5 = base + (q ^ 5);
        const float4* p6 = base + (q ^ 6);
        const float4* p7 = base + (q ^ 7);

        float acc = 0.f;
        for (int c = 0; c < 256; c += 8) {
            float4 yv[8] = { p0[c], p1[c], p2[c], p3[c], p4[c], p5[c], p6[c], p7[c] };
            #pragma unroll
            for (int k = 0; k < 8; ++k) {
                float4 yj = yv[k];
                float d  = fmaf(yj.x, xf.x, fmaf(yj.y, xf.y, yj.z * xf.z));
                float y2 = fmaf(yj.x, yj.x, fmaf(yj.y, yj.y, yj.z * yj.z));
                float C  = fmaf(-2.0f, d, xf.w + y2);
                float t  = fmaf(K_TWO_R, d, u2 + yj.w);
                acc = fmaf(fexp2(t), C, acc);
            }
        }
        #pragma unroll
        for (int off = 1; off < 64; off <<= 1) acc += __shfl_xor(acc, off, 64);

        __syncthreads();                 // done reading panel; reuse as scratch
        float* wsum = (float*)ld;
        if ((tid & 63) == 0) wsum[tid >> 6] = acc;
        __syncthreads();
        if (tid == 0) atomicAdd(&out[b], wsum[0] + wsum[1] + wsum[2] + wsum[3]);
    }
}

// -------------------------------------------------------------- launch ------
extern "C" void kernel_launch(void* const* d_in, const int* in_sizes, int n_in,
                              void* d_out, int out_size, void* d_ws, size_t ws_size,
                              hipStream_t stream)
{
    const float* x = (const float*)d_in[0];
    const float* y = (const float*)d_in[1];
    float* out = (float*)d_out;

    char* ws = (char*)d_ws;
    float4*   px  = (float4*)(ws);
    float4*   py  = (float4*)(ws + (size_t)NB * NPTS * 16);
    float*    f   = (float*)  (ws + (size_t)NB * NPTS * 32);
    float*    g   = (float*)  (ws + (size_t)NB * NPTS * 32 + (size_t)NB * NPTS * 4);
    unsigned* bar = (unsigned*)(ws + (size_t)NB * NPTS * 32 + (size_t)NB * NPTS * 8);

    hipMemsetAsync(d_out, 0, (size_t)out_size * sizeof(float), stream);
    hipMemsetAsync(bar, 0, NB * 32 * sizeof(unsigned), stream);

    prep_kernel<<<(NB * NPTS + 255) / 256, 256, 0, stream>>>(x, y, px, py, g);
    sinkhorn_fused<<<NB * 64, 256, 0, stream>>>(px, py, f, g, bar, out);
}

// Round 6
// 1525.242 us; speedup vs baseline: 3.2437x; 1.4799x over previous
//
#include <hip/hip_runtime.h>

#define NPTS 2048
#define NB   16

// eps = 0.01, log-domain Sinkhorn in base-2.
constexpr float K_R          = 144.26950408889634f;    // log2(e)/eps
constexpr float K_TWO_R      = 288.53900817779268f;    // 2*K_R
constexpr float K_EPS_LN2    = 0.0069314718055994531f; // eps*ln2
constexpr float K_EPS_LOGMRG = -0.076246189861593985f; // eps*ln(1/2048)

__device__ __forceinline__ float fexp2(float x) { return __builtin_amdgcn_exp2f(x); }
__device__ __forceinline__ float flog2(float x) { return __builtin_amdgcn_logf(x); }

// ---------------------------------------------------------------- prep ------
__global__ __launch_bounds__(256) void prep_kernel(
    const float* __restrict__ x, const float* __restrict__ y,
    float4* __restrict__ px, float4* __restrict__ py, float* __restrict__ g)
{
    int idx = blockIdx.x * 256 + threadIdx.x;
    if (idx >= NB * NPTS) return;
    float x0 = x[idx*3+0], x1 = x[idx*3+1], x2 = x[idx*3+2];
    px[idx] = make_float4(x0, x1, x2, fmaf(x0,x0, fmaf(x1,x1, x2*x2)));
    float y0 = y[idx*3+0], y1 = y[idx*3+1], y2 = y[idx*3+2];
    py[idx] = make_float4(y0, y1, y2, fmaf(y0,y0, fmaf(y1,y1, y2*y2)));
    g[idx] = 0.0f;
}

// ------------------------------------------------------------ half step -----
// dual_out[i] = eps*log(1/N) - eps*ln2 * log2( sum_j 2^{(dual_j - C_ij)*R} )
// Register-tiled: each wave owns 8 rows (xi in VGPRs); 64 lanes j-split.
// One ds_read_b128 feeds 8 row-visits -> LDS traffic 2 B/visit (was 16).
// Grid: 1024 wgs (64/batch), 256 thr = 4 waves -> 32 rows/wg.
__global__ __launch_bounds__(256) void half_step(
    const float4* __restrict__ pcol, const float* __restrict__ dual_in,
    const float4* __restrict__ prow, float* __restrict__ dual_out)
{
    __shared__ float4 ld[NPTS];   // (y*2R, (dual-|y|^2)*R), linear layout

    const int b     = blockIdx.x >> 6;
    const int chunk = blockIdx.x & 63;
    const int tid   = threadIdx.x;

    const float4* pc = pcol    + b * NPTS;
    const float*  di = dual_in + b * NPTS;

    #pragma unroll
    for (int i2 = 0; i2 < 8; ++i2) {
        int k = i2 * 256 + tid;
        float4 p = pc[k];
        ld[k] = make_float4(p.x * K_TWO_R, p.y * K_TWO_R, p.z * K_TWO_R,
                            (di[k] - p.w) * K_R);
    }

    const int lane = tid & 63;
    const int wid  = tid >> 6;
    const int row0 = chunk * 32 + wid * 8;

    float rx[8], ry[8], rz[8], u0[8];
    #pragma unroll
    for (int r = 0; r < 8; ++r) {
        float4 xi = prow[b * NPTS + row0 + r];
        rx[r] = xi.x; ry[r] = xi.y; rz[r] = xi.z; u0[r] = -xi.w * K_R;
    }

    __syncthreads();

    float acc[8] = {0.f,0.f,0.f,0.f,0.f,0.f,0.f,0.f};
    for (int c = 0; c < 32; c += 2) {
        float4 ya = ld[(c    ) * 64 + lane];
        float4 yb = ld[(c + 1) * 64 + lane];
        #pragma unroll
        for (int r = 0; r < 8; ++r) {
            float wa = fmaf(ya.x, rx[r], fmaf(ya.y, ry[r], fmaf(ya.z, rz[r], ya.w + u0[r])));
            acc[r] += fexp2(wa);
        }
        #pragma unroll
        for (int r = 0; r < 8; ++r) {
            float wb = fmaf(yb.x, rx[r], fmaf(yb.y, ry[r], fmaf(yb.z, rz[r], yb.w + u0[r])));
            acc[r] += fexp2(wb);
        }
    }

    #pragma unroll
    for (int r = 0; r < 8; ++r) {
        #pragma unroll
        for (int off = 1; off < 64; off <<= 1)
            acc[r] += __shfl_xor(acc[r], off, 64);
    }
    if (lane < 8) {
        float s = acc[0];
        #pragma unroll
        for (int r = 1; r < 8; ++r) s = (lane == r) ? acc[r] : s;
        dual_out[b * NPTS + row0 + lane] =
            K_EPS_LOGMRG - K_EPS_LN2 * flog2(s);
    }
}

// ---------------------------------------------------------------- emd -------
// out[b] = sum_ij 2^{(f_i + g_j - C_ij)*R} * C_ij, same register tiling.
__global__ __launch_bounds__(256) void emd_kernel(
    const float4* __restrict__ px, const float4* __restrict__ py,
    const float* __restrict__ f, const float* __restrict__ g,
    float* __restrict__ out)
{
    __shared__ float4 ld[NPTS];   // (y raw, |y|^2)
    __shared__ float  hh[NPTS];   // (g-|y|^2)*R
    __shared__ float  wsum[4];

    const int b     = blockIdx.x >> 6;
    const int chunk = blockIdx.x & 63;
    const int tid   = threadIdx.x;

    #pragma unroll
    for (int i2 = 0; i2 < 8; ++i2) {
        int k = i2 * 256 + tid;
        float4 p = py[b * NPTS + k];
        ld[k] = p;
        hh[k] = (g[b * NPTS + k] - p.w) * K_R;
    }

    const int lane = tid & 63;
    const int wid  = tid >> 6;
    const int row0 = chunk * 32 + wid * 8;

    float rx[8], ry[8], rz[8], rw[8], u2[8];
    #pragma unroll
    for (int r = 0; r < 8; ++r) {
        float4 xi = px[b * NPTS + row0 + r];
        rx[r] = xi.x; ry[r] = xi.y; rz[r] = xi.z; rw[r] = xi.w;
        u2[r] = (f[b * NPTS + row0 + r] - xi.w) * K_R;
    }

    __syncthreads();

    float acc = 0.f;
    for (int c = 0; c < 32; ++c) {
        float4 yj = ld[c * 64 + lane];
        float  hj = hh[c * 64 + lane];
        #pragma unroll
        for (int r = 0; r < 8; ++r) {
            float d = fmaf(yj.x, rx[r], fmaf(yj.y, ry[r], yj.z * rz[r]));
            float C = fmaf(-2.0f, d, rw[r] + yj.w);
            float t = fmaf(K_TWO_R, d, u2[r] + hj);
            acc = fmaf(fexp2(t), C, acc);
        }
    }

    #pragma unroll
    for (int off = 1; off < 64; off <<= 1) acc += __shfl_xor(acc, off, 64);
    if (lane == 0) wsum[wid] = acc;
    __syncthreads();
    if (tid == 0) atomicAdd(&out[b], wsum[0] + wsum[1] + wsum[2] + wsum[3]);
}

// -------------------------------------------------------------- launch ------
extern "C" void kernel_launch(void* const* d_in, const int* in_sizes, int n_in,
                              void* d_out, int out_size, void* d_ws, size_t ws_size,
                              hipStream_t stream)
{
    const float* x = (const float*)d_in[0];
    const float* y = (const float*)d_in[1];
    float* out = (float*)d_out;

    char* ws = (char*)d_ws;
    float4* px = (float4*)(ws);
    float4* py = (float4*)(ws + (size_t)NB * NPTS * 16);
    float*  f  = (float*) (ws + (size_t)NB * NPTS * 32);
    float*  g  = (float*) (ws + (size_t)NB * NPTS * 32 + (size_t)NB * NPTS * 4);

    hipMemsetAsync(d_out, 0, (size_t)out_size * sizeof(float), stream);

    prep_kernel<<<(NB * NPTS + 255) / 256, 256, 0, stream>>>(x, y, px, py, g);

    for (int it = 0; it < 50; ++it) {
        half_step<<<1024, 256, 0, stream>>>(py, g, px, f);  // f-update
        half_step<<<1024, 256, 0, stream>>>(px, f, py, g);  // g-update
    }

    emd_kernel<<<1024, 256, 0, stream>>>(px, py, f, g, out);
}